// Round 7
// baseline (1987.420 us; speedup 1.0000x reference)
//
#include <hip/hip_runtime.h>
#include <hip/hip_bf16.h>

// Model dims (fixed)
#define DIMM 128
#define TT   40
#define BB   4096
#define NTOK (BB*TT)           // 163840
#define CHTOK (NTOK/2)         // 81920 tokens per chunk (qkv scratch)
#define NLAY 3

typedef float f4 __attribute__((ext_vector_type(4)));
typedef float f32x4 __attribute__((ext_vector_type(4)));
typedef short bf16x8 __attribute__((ext_vector_type(8)));

__device__ __forceinline__ float bf2f(unsigned short u) {
    union { unsigned int i; float f; } v; v.i = ((unsigned int)u) << 16; return v.f;
}
__device__ __forceinline__ unsigned short f2bu(float f) {
    __hip_bfloat16 h = __float2bfloat16(f);
    return *reinterpret_cast<unsigned short*>(&h);
}

// per-row mln stats from registers: v[8] = row values at cols nf*16+l15 (16 lanes hold full row)
__device__ __forceinline__ void mln_rowstat(
    const float* v, const float* pgv, const float* pbv,
    float& m, float& rstd, float& mq)
{
    float s1 = 0.f, s2 = 0.f;
    #pragma unroll
    for (int nf = 0; nf < 8; ++nf) { s1 += v[nf]; s2 += v[nf]*v[nf]; }
    #pragma unroll
    for (int o = 1; o < 16; o <<= 1) { s1 += __shfl_xor(s1, o); s2 += __shfl_xor(s2, o); }
    m = s1 * (1.f/128.f);
    float var = s2 * (1.f/128.f) - m*m;
    rstd = rsqrtf(fmaxf(var, 0.f) + 1e-5f);
    float q = 0.f;
    #pragma unroll
    for (int nf = 0; nf < 8; ++nf) {
        float yv = (v[nf] - m) * rstd * pgv[nf] + pbv[nf];
        q += (nf < 2 ? -(yv*yv) : (yv*yv));     // cols 0..31 = "t" part (negative)
    }
    #pragma unroll
    for (int o = 1; o < 16; o <<= 1) q += __shfl_xor(q, o);
    mq = q;
}

// ---------------- pack ALL weights to bf16, transposed W^T[n][k] ----------------
__global__ __launch_bounds__(256) void pack_w_k(
    const float* __restrict__ qt, const float* __restrict__ kt,
    const float* __restrict__ qs, const float* __restrict__ ks,
    const float* __restrict__ vw, const float* __restrict__ ow,
    const float* __restrict__ w1, const float* __restrict__ w2,
    unsigned short* __restrict__ wqT, unsigned short* __restrict__ outT,
    unsigned short* __restrict__ ff1T, unsigned short* __restrict__ ff2T)
{
    int idx = blockIdx.x * 256 + threadIdx.x;          // 589824 total
    if (idx < 147456) {
        int i = idx / 49152, r = idx % 49152;
        int n = r / 128, k = r % 128;
        float v;
        if (n < 32)        v = qt[i*4096  + k*32  + n];
        else if (n < 64)   v = kt[i*4096  + k*32  + (n-32)];
        else if (n < 160)  v = qs[i*12288 + k*96  + (n-64)];
        else if (n < 256)  v = ks[i*12288 + k*96  + (n-160)];
        else               v = vw[i*16384 + k*128 + (n-256)];
        wqT[idx] = f2bu(v);
    } else if (idx < 196608) {
        int j = idx - 147456;
        int i = j / 16384, r = j % 16384;
        int n = r / 128, k = r % 128;
        outT[j] = f2bu(ow[i*16384 + k*128 + n]);
    } else if (idx < 393216) {
        int j = idx - 196608;
        int i = j / 65536, r = j % 65536;
        int n = r / 128, k = r % 128;
        ff1T[j] = f2bu(w1[i*65536 + k*512 + n]);
    } else {
        int j = idx - 393216;
        int i = j / 65536, r = j % 65536;
        int n = r / 512, k = r % 512;
        ff2T[j] = f2bu(w2[i*65536 + k*128 + n]);
    }
}

// ---------------- embedding: h = x @ embed_w + embed_b + pos ----------------
__global__ __launch_bounds__(256) void embed_k(
    const float* __restrict__ x, const float* __restrict__ ew,
    const float* __restrict__ eb, const float* __restrict__ pos,
    float* __restrict__ h)
{
    int idx = blockIdx.x * 256 + threadIdx.x;      // NTOK*128
    int n = idx >> 7, d = idx & 127;
    int t = n % TT;
    const float* xr = x + (size_t)n * 6;
    float acc = eb[d] + pos[t*128 + d];
    #pragma unroll
    for (int k = 0; k < 6; ++k) acc += xr[k] * ew[k*128 + d];
    h[idx] = acc;
}

// ---------------- mln stats (standalone — only after embed) ----------------
__global__ __launch_bounds__(256) void mln_stats_k(
    const float* __restrict__ h, const float* __restrict__ pg, const float* __restrict__ pb,
    float* __restrict__ stats, float* __restrict__ partials)
{
    int wid = threadIdx.x >> 6, lane = threadIdx.x & 63;
    int tok = blockIdx.x * 4 + wid;
    const float* hr = h + (size_t)tok * 128;
    float x0 = hr[lane], x1 = hr[lane + 64];
    float s = x0 + x1;
    #pragma unroll
    for (int o = 32; o > 0; o >>= 1) s += __shfl_xor(s, o);
    float m = s * (1.f / 128.f);
    float d0 = x0 - m, d1 = x1 - m;
    float v = d0*d0 + d1*d1;
    #pragma unroll
    for (int o = 32; o > 0; o >>= 1) v += __shfl_xor(v, o);
    float rstd = rsqrtf(v * (1.f / 128.f) + 1e-5f);
    float y0 = d0 * rstd * pg[lane]      + pb[lane];
    float y1 = d1 * rstd * pg[lane + 64] + pb[lane + 64];
    float q = (lane < 32 ? -(y0*y0) : (y0*y0)) + y1*y1;
    #pragma unroll
    for (int o = 32; o > 0; o >>= 1) q += __shfl_xor(q, o);
    if (lane == 0) {
        stats[(size_t)tok*4 + 0] = m;
        stats[(size_t)tok*4 + 1] = rstd;
        stats[(size_t)tok*4 + 2] = q;
    }
    __shared__ float pm[4];
    if (lane == 0) pm[wid] = fabsf(q);
    __syncthreads();
    if (threadIdx.x == 0) partials[blockIdx.x] = (pm[0] + pm[1]) + (pm[2] + pm[3]);
}

// ---------------- reduce partials -> eps scalar (deterministic) ----------------
__global__ __launch_bounds__(1024) void reduce_eps_k(
    const float* __restrict__ partials, int n, float* __restrict__ scal)
{
    float s = 0.f;
    for (int i = threadIdx.x; i < n; i += 1024) s += partials[i];
    __shared__ float sm[1024];
    sm[threadIdx.x] = s;
    __syncthreads();
    for (int o = 512; o > 0; o >>= 1) {
        if (threadIdx.x < o) sm[threadIdx.x] += sm[threadIdx.x + o];
        __syncthreads();
    }
    if (threadIdx.x == 0) {
        float mean = sm[0] / (float)NTOK;
        scal[0] = fmaxf(0.01f * mean, 1e-5f);
    }
}

// ---------------- apply mln: y = g*(ln(x)*s3)+b  -> bf16 ----------------
__global__ __launch_bounds__(256) void mln_apply_k(
    const float* __restrict__ h, const float* __restrict__ stats, const float* __restrict__ scal,
    const float* __restrict__ pg, const float* __restrict__ pb,
    const float* __restrict__ gg, const float* __restrict__ gb,
    unsigned short* __restrict__ y)
{
    int gid = blockIdx.x * 256 + threadIdx.x;      // NTOK*32
    int tok = gid >> 5, c4 = (gid & 31) << 2;
    float eps = scal[0];
    float m  = stats[(size_t)tok*4 + 0];
    float rs = stats[(size_t)tok*4 + 1];
    float mq = stats[(size_t)tok*4 + 2];
    float s3 = 1.f / (sqrtf(fabsf(mq) + eps) + eps);
    f4 x = *(const f4*)(h + (size_t)tok*128 + c4);
    ushort4 o;
    float v0 = gg[c4+0] * (((x[0]-m)*rs*pg[c4+0] + pb[c4+0]) * s3) + gb[c4+0];
    float v1 = gg[c4+1] * (((x[1]-m)*rs*pg[c4+1] + pb[c4+1]) * s3) + gb[c4+1];
    float v2 = gg[c4+2] * (((x[2]-m)*rs*pg[c4+2] + pb[c4+2]) * s3) + gb[c4+2];
    float v3 = gg[c4+3] * (((x[3]-m)*rs*pg[c4+3] + pb[c4+3]) * s3) + gb[c4+3];
    o.x = f2bu(v0); o.y = f2bu(v1); o.z = f2bu(v2); o.w = f2bu(v3);
    *(ushort4*)(y + (size_t)tok*128 + c4) = o;
}

// ---------------- 128-col-tile MFMA GEMM, B-frags from global (L2) ----------------
// C[128rows x 128cols] = A[128][128](bf16) @ BT[col][128]^T ; 4 waves x 32 rows
// EPI 0: bf16 store to obuf (no bias)           [QKV]
// EPI 2: hres += v+bias, THEN per-row mln stats  [out-proj]
template<int EPI>
__global__ __launch_bounds__(256) void gemm128_k(
    const unsigned short* __restrict__ A,
    const unsigned short* __restrict__ BT,
    const float* __restrict__ bias,
    unsigned short* __restrict__ obuf, int ldo,
    float* __restrict__ hres,
    const float* __restrict__ pre_g, const float* __restrict__ pre_b,
    float* __restrict__ stats, float* __restrict__ partials)
{
    __shared__ unsigned char As[128*272];
    __shared__ float sm[32];
    const int tid = threadIdx.x, wid = tid >> 6, lane = tid & 63;
    const int q = lane >> 4, l15 = lane & 15;
    const int row0 = blockIdx.y * 128, col0 = blockIdx.x * 128;
    const int wrow = wid * 32;

    {
        int row = tid >> 4, q8 = (tid & 15) << 3;
        #pragma unroll
        for (int p = 0; p < 8; ++p, row += 16) {
            uint4 av = *(const uint4*)(A + (size_t)(row0 + row)*128 + q8);
            *(uint4*)(As + row*272 + q8*2) = av;
        }
    }
    __syncthreads();

    f32x4 acc[2][8] = {};
    #pragma unroll
    for (int ks = 0; ks < 4; ++ks) {
        bf16x8 a[2];
        #pragma unroll
        for (int mf = 0; mf < 2; ++mf)
            a[mf] = *(const bf16x8*)(As + (wrow + mf*16 + l15)*272 + ks*64 + q*16);
        #pragma unroll
        for (int nf = 0; nf < 8; ++nf) {
            bf16x8 b = *(const bf16x8*)(BT + (size_t)(col0 + nf*16 + l15)*128 + ks*32 + q*8);
            #pragma unroll
            for (int mf = 0; mf < 2; ++mf)
                acc[mf][nf] = __builtin_amdgcn_mfma_f32_16x16x32_bf16(a[mf], b, acc[mf][nf], 0, 0, 0);
        }
    }

    if (EPI == 0) {
        #pragma unroll
        for (int mf = 0; mf < 2; ++mf)
            #pragma unroll
            for (int r = 0; r < 4; ++r) {
                int row = row0 + wrow + mf*16 + q*4 + r;
                #pragma unroll
                for (int nf = 0; nf < 8; ++nf)
                    obuf[(size_t)row*ldo + col0 + nf*16 + l15] = f2bu(acc[mf][nf][r]);
            }
    } else {
        float bv[8], pgv[8], pbv[8];
        #pragma unroll
        for (int nf = 0; nf < 8; ++nf) {
            int c = nf*16 + l15;
            bv[nf] = bias[c]; pgv[nf] = pre_g[c]; pbv[nf] = pre_b[c];
        }
        float amq = 0.f;
        #pragma unroll
        for (int mf = 0; mf < 2; ++mf) {
            #pragma unroll
            for (int r = 0; r < 4; ++r) {
                int row = row0 + wrow + mf*16 + q*4 + r;
                float* hr = hres + (size_t)row*128;
                float v[8];
                #pragma unroll
                for (int nf = 0; nf < 8; ++nf) {
                    float hv = hr[nf*16 + l15] + acc[mf][nf][r] + bv[nf];
                    hr[nf*16 + l15] = hv;
                    v[nf] = hv;
                }
                float m, rstd, mq;
                mln_rowstat(v, pgv, pbv, m, rstd, mq);
                if (l15 == 0) {
                    stats[(size_t)row*4 + 0] = m;
                    stats[(size_t)row*4 + 1] = rstd;
                    stats[(size_t)row*4 + 2] = mq;
                }
                amq += fabsf(mq);
            }
        }
        if (l15 == 0) sm[wid*4 + q] = amq;
        __syncthreads();
        if (tid == 0) {
            float s = 0.f;
            #pragma unroll
            for (int j = 0; j < 16; ++j) s += sm[j];
            partials[blockIdx.y] = s;
        }
    }
}

// ---------------- fused FFN: h += gelu(y@W1+b1)@W2 + b2, + mln stats ----------------
// 8 waves x 16 rows (512 threads) for latency hiding
__global__ __launch_bounds__(512) void ffn_k(
    const unsigned short* __restrict__ y,     // [NTOK][128] bf16
    const unsigned short* __restrict__ W1T,   // [512][128] bf16
    const float* __restrict__ b1,             // [512]
    const unsigned short* __restrict__ W2T,   // [128][512] bf16
    const float* __restrict__ b2,             // [128]
    float* __restrict__ h,                    // [NTOK][128] f32, +=
    const float* __restrict__ pre_g, const float* __restrict__ pre_b,
    float* __restrict__ stats, float* __restrict__ partials)
{
    __shared__ unsigned char As[128*272];
    __shared__ unsigned char Ps[128*144];
    __shared__ float sm[32];
    const int tid = threadIdx.x, wid = tid >> 6, lane = tid & 63;
    const int q = lane >> 4, l15 = lane & 15;
    const int row0 = blockIdx.x * 128;
    const int wrow = wid * 16;

    {
        int row = tid >> 4, q8 = (tid & 15) << 3;
        #pragma unroll
        for (int p = 0; p < 4; ++p, row += 32) {
            uint4 av = *(const uint4*)(y + (size_t)(row0 + row)*128 + q8);
            *(uint4*)(As + row*272 + q8*2) = av;
        }
    }
    __syncthreads();

    float b2v[8];
    #pragma unroll
    for (int nf = 0; nf < 8; ++nf) b2v[nf] = b2[nf*16 + l15];

    f32x4 acc2[8] = {};

    for (int c = 0; c < 8; ++c) {
        f32x4 acc1[4] = {};
        #pragma unroll
        for (int ks = 0; ks < 4; ++ks) {
            bf16x8 a = *(const bf16x8*)(As + (wrow + l15)*272 + ks*64 + q*16);
            #pragma unroll
            for (int nf = 0; nf < 4; ++nf) {
                bf16x8 b = *(const bf16x8*)(W1T + (size_t)(c*64 + nf*16 + l15)*128 + ks*32 + q*8);
                acc1[nf] = __builtin_amdgcn_mfma_f32_16x16x32_bf16(a, b, acc1[nf], 0, 0, 0);
            }
        }
        // bias + exact gelu -> Ps (wave-private rows)
        #pragma unroll
        for (int nf = 0; nf < 4; ++nf) {
            float bb = b1[c*64 + nf*16 + l15];
            #pragma unroll
            for (int r = 0; r < 4; ++r) {
                float v = acc1[nf][r] + bb;
                v = 0.5f * v * (1.f + erff(v * 0.70710678118654752f));
                *(unsigned short*)(Ps + (wrow + q*4 + r)*144 + (nf*16 + l15)*2) = f2bu(v);
            }
        }
        #pragma unroll
        for (int ks2 = 0; ks2 < 2; ++ks2) {
            bf16x8 a2 = *(const bf16x8*)(Ps + (wrow + l15)*144 + ks2*64 + q*16);
            #pragma unroll
            for (int nf = 0; nf < 8; ++nf) {
                bf16x8 b = *(const bf16x8*)(W2T + (size_t)(nf*16 + l15)*512 + c*64 + ks2*32 + q*8);
                acc2[nf] = __builtin_amdgcn_mfma_f32_16x16x32_bf16(a2, b, acc2[nf], 0, 0, 0);
            }
        }
    }
    // epilogue: h += acc2 + b2, then per-row stats for the NEXT mln
    float pgv[8], pbv[8];
    #pragma unroll
    for (int nf = 0; nf < 8; ++nf) { pgv[nf] = pre_g[nf*16 + l15]; pbv[nf] = pre_b[nf*16 + l15]; }
    float amq = 0.f;
    #pragma unroll
    for (int r = 0; r < 4; ++r) {
        int row = row0 + wrow + q*4 + r;
        float* hr = h + (size_t)row*128;
        float v[8];
        #pragma unroll
        for (int nf = 0; nf < 8; ++nf) {
            float hv = hr[nf*16 + l15] + acc2[nf][r] + b2v[nf];
            hr[nf*16 + l15] = hv;
            v[nf] = hv;
        }
        float m, rstd, mq;
        mln_rowstat(v, pgv, pbv, m, rstd, mq);
        if (l15 == 0) {
            stats[(size_t)row*4 + 0] = m;
            stats[(size_t)row*4 + 1] = rstd;
            stats[(size_t)row*4 + 2] = mq;
        }
        amq += fabsf(mq);
    }
    if (l15 == 0) sm[wid*4 + q] = amq;
    __syncthreads();
    if (tid == 0) {
        float s = 0.f;
        #pragma unroll
        for (int j = 0; j < 32; ++j) s += sm[j];
        partials[blockIdx.x] = s;
    }
}

// ---------------- attention: block per (chunk-local) batch, THREAD per (head, query) ----------------
__global__ __launch_bounds__(256) void attn_k(
    const unsigned short* __restrict__ qkv,
    unsigned short* __restrict__ yout,
    const float* __restrict__ wsp)
{
    __shared__ float Kl[4][40][32];
    __shared__ float Vl[4][40][32];
    int b = blockIdx.x;
    int tid = threadIdx.x;

    for (int e = tid; e < 1280; e += 256) {
        int r = e >> 3, q4 = (e & 7) << 2;
        int h = r / 40, t = r - h * 40;
        int hx = h << 2;
        const unsigned short* src = qkv + (size_t)(b*TT + t) * 384;
        int kcol = (h == 0) ? 32 : 128 + h*32;
        ushort4 uk = *(const ushort4*)(src + kcol + q4);
        ushort4 uv = *(const ushort4*)(src + 256 + h*32 + q4);
        f4 fk, fv;
        fk[0]=bf2f(uk.x); fk[1]=bf2f(uk.y); fk[2]=bf2f(uk.z); fk[3]=bf2f(uk.w);
        fv[0]=bf2f(uv.x); fv[1]=bf2f(uv.y); fv[2]=bf2f(uv.z); fv[3]=bf2f(uv.w);
        *(f4*)(&Kl[h][t][q4 ^ hx]) = fk;
        *(f4*)(&Vl[h][t][q4 ^ hx]) = fv;
    }
    __syncthreads();
    if (tid >= 160) return;

    int h = tid / 40, t = tid - h * 40;
    int hx = h << 2;
    const unsigned short* qrow = qkv + (size_t)(b*TT + t) * 384;
    int qcol = (h == 0) ? 0 : 32 + h*32;

    float q[32];
    #pragma unroll
    for (int k = 0; k < 32; k += 4) {
        ushort4 u = *(const ushort4*)(qrow + qcol + k);
        q[k]=bf2f(u.x); q[k+1]=bf2f(u.y); q[k+2]=bf2f(u.z); q[k+3]=bf2f(u.w);
    }
    const float scale = 0.17677669529663687f;   // 32^-0.5
    float wmul = scale;
    if (h == 0) wmul = -scale / (1.f + __expf(-wsp[0]));

    float sc[40];
    float mx = -1e30f;
    #pragma unroll
    for (int s = 0; s < 40; ++s) {
        float dot = 0.f;
        #pragma unroll
        for (int k = 0; k < 32; k += 4) {
            const f4 kv = *(const f4*)(&Kl[h][s][k ^ hx]);
            dot += q[k]*kv[0] + q[k+1]*kv[1] + q[k+2]*kv[2] + q[k+3]*kv[3];
        }
        float v = wmul * dot;
        sc[s] = v;
        mx = fmaxf(mx, v);
    }
    float sum = 0.f;
    #pragma unroll
    for (int s = 0; s < 40; ++s) { float p = __expf(sc[s] - mx); sc[s] = p; sum += p; }
    float inv = 1.f / sum;

    float acc[32] = {};
    #pragma unroll
    for (int s = 0; s < 40; ++s) {
        float p = sc[s];
        #pragma unroll
        for (int k = 0; k < 32; k += 4) {
            const f4 vv = *(const f4*)(&Vl[h][s][k ^ hx]);
            acc[k]   += p*vv[0]; acc[k+1] += p*vv[1];
            acc[k+2] += p*vv[2]; acc[k+3] += p*vv[3];
        }
    }
    unsigned short* orow = yout + (size_t)(b*TT + t) * 128 + h*32;
    #pragma unroll
    for (int k = 0; k < 32; k += 4) {
        ushort4 u;
        u.x = f2bu(acc[k]  *inv); u.y = f2bu(acc[k+1]*inv);
        u.z = f2bu(acc[k+2]*inv); u.w = f2bu(acc[k+3]*inv);
        *(ushort4*)(orow + k) = u;
    }
}

// ---------------- head: last token y (bf16) @ traj_w + traj_b (f32 out) ----------------
__global__ __launch_bounds__(128) void head_k(
    const unsigned short* __restrict__ y,
    const float* __restrict__ tw, const float* __restrict__ tb,
    float* __restrict__ out)
{
    int b = blockIdx.x, tid = threadIdx.x;
    int tok = b*TT + (TT - 1);
    __shared__ float ys[128];
    ys[tid] = bf2f(y[(size_t)tok*128 + tid]);
    __syncthreads();
    if (tid < 120) {
        float acc = tb[tid];
        #pragma unroll 4
        for (int d = 0; d < 128; ++d) acc += ys[d] * tw[d*120 + tid];
        out[(size_t)b*120 + tid] = acc;
    }
}

extern "C" void kernel_launch(void* const* d_in, const int* in_sizes, int n_in,
                              void* d_out, int out_size, void* d_ws, size_t ws_size,
                              hipStream_t stream) {
    const float* x        = (const float*)d_in[0];
    const float* embed_w  = (const float*)d_in[1];
    const float* embed_b  = (const float*)d_in[2];
    const float* pos      = (const float*)d_in[3];
    const float* qt_w     = (const float*)d_in[4];
    const float* kt_w     = (const float*)d_in[5];
    const float* qs_w     = (const float*)d_in[6];
    const float* ks_w     = (const float*)d_in[7];
    const float* v_w      = (const float*)d_in[8];
    const float* out_w    = (const float*)d_in[9];
    const float* out_b    = (const float*)d_in[10];
    const float* w_sigma  = (const float*)d_in[11];
    const float* n1_pre_g = (const float*)d_in[12];
    const float* n1_pre_b = (const float*)d_in[13];
    const float* n1_g     = (const float*)d_in[14];
    const float* n1_b     = (const float*)d_in[15];
    const float* n2_pre_g = (const float*)d_in[16];
    const float* n2_pre_b = (const float*)d_in[17];
    const float* n2_g     = (const float*)d_in[18];
    const float* n2_b     = (const float*)d_in[19];
    const float* ff_w1    = (const float*)d_in[20];
    const float* ff_b1    = (const float*)d_in[21];
    const float* ff_w2    = (const float*)d_in[22];
    const float* ff_b2    = (const float*)d_in[23];
    const float* fn_pre_g = (const float*)d_in[24];
    const float* fn_pre_b = (const float*)d_in[25];
    const float* fn_g     = (const float*)d_in[26];
    const float* fn_b     = (const float*)d_in[27];
    const float* traj_w   = (const float*)d_in[28];
    const float* traj_b   = (const float*)d_in[29];

    // ---- workspace layout (total ~192.7 MB) ----
    char* ws = (char*)d_ws;
    float*          h       = (float*)ws;                           //  83,886,080 B
    float*          stats   = (float*)(ws + 83886080);              //   2,621,440 B
    unsigned short* y       = (unsigned short*)(ws + 86507520);     //  41,943,040 B (NTOK x 128 bf16)
    unsigned short* scratch = (unsigned short*)(ws + 128450560);    //  62,914,560 B (CHTOK x 384 bf16)
    unsigned short* wqT     = (unsigned short*)(ws + 191365120);    //     294,912 B
    unsigned short* outT    = (unsigned short*)(ws + 191660032);    //      98,304 B
    unsigned short* ff1T    = (unsigned short*)(ws + 191758336);    //     393,216 B
    unsigned short* ff2T    = (unsigned short*)(ws + 192151552);    //     393,216 B
    float*          partials= (float*)(ws + 192544768);             //     163,840 B
    float*          scal    = (float*)(ws + 192708608);             //         256 B

    pack_w_k<<<2304, 256, 0, stream>>>(qt_w, kt_w, qs_w, ks_w, v_w, out_w, ff_w1, ff_w2,
                                       wqT, outT, ff1T, ff2T);
    embed_k<<<81920, 256, 0, stream>>>(x, embed_w, embed_b, pos, h);

    // stats for mln1 of layer 0 (only standalone stats pass)
    mln_stats_k<<<40960, 256, 0, stream>>>(h, n1_pre_g, n1_pre_b, stats, partials);
    reduce_eps_k<<<1, 1024, 0, stream>>>(partials, 40960, scal);

    for (int i = 0; i < NLAY; ++i) {
        // ---- mln1 apply + attention block ----
        mln_apply_k<<<20480, 256, 0, stream>>>(h, stats, scal, n1_pre_g + i*128, n1_pre_b + i*128,
                                               n1_g + i*128, n1_b + i*128, y);
        for (int c = 0; c < 2; ++c) {
            size_t off = (size_t)c * CHTOK;
            gemm128_k<0><<<dim3(3, 640), 256, 0, stream>>>(
                y + off*128, wqT + (size_t)i*49152, nullptr, scratch, 384,
                nullptr, nullptr, nullptr, nullptr, nullptr);
            attn_k<<<2048, 256, 0, stream>>>(scratch, y + off*128, w_sigma + i);
            gemm128_k<2><<<dim3(1, 640), 256, 0, stream>>>(
                y + off*128, outT + (size_t)i*16384, out_b + i*128, nullptr, 0,
                h + off*128, n2_pre_g + i*128, n2_pre_b + i*128,
                stats + off*4, partials + c*640);
        }
        reduce_eps_k<<<1, 1024, 0, stream>>>(partials, 1280, scal);
        // ---- mln2 apply + fused FFN (stats for next mln1 / final fn) ----
        mln_apply_k<<<20480, 256, 0, stream>>>(h, stats, scal, n2_pre_g + i*128, n2_pre_b + i*128,
                                               n2_g + i*128, n2_b + i*128, y);
        const float* npg = (i < NLAY-1) ? (n1_pre_g + (i+1)*128) : fn_pre_g;
        const float* npb = (i < NLAY-1) ? (n1_pre_b + (i+1)*128) : fn_pre_b;
        ffn_k<<<1280, 512, 0, stream>>>(y, ff1T + (size_t)i*65536, ff_b1 + i*512,
                                        ff2T + (size_t)i*65536, ff_b2 + i*128, h,
                                        npg, npb, stats, partials);
        reduce_eps_k<<<1, 1024, 0, stream>>>(partials, 1280, scal);
    }

    // ---- final mln apply + head ----
    mln_apply_k<<<20480, 256, 0, stream>>>(h, stats, scal, fn_pre_g, fn_pre_b, fn_g, fn_b, y);
    head_k<<<4096, 128, 0, stream>>>(y, traj_w, traj_b, (float*)d_out);
}

// Round 8
// 1760.607 us; speedup vs baseline: 1.1288x; 1.1288x over previous
//
#include <hip/hip_runtime.h>
#include <hip/hip_bf16.h>

// Model dims (fixed)
#define DIMM 128
#define TT   40
#define BB   4096
#define NTOK (BB*TT)           // 163840
#define CHTOK (NTOK/2)         // 81920 tokens per chunk (qkv scratch)
#define NLAY 3

typedef float f4 __attribute__((ext_vector_type(4)));
typedef float f32x4 __attribute__((ext_vector_type(4)));
typedef short bf16x8 __attribute__((ext_vector_type(8)));

__device__ __forceinline__ float bf2f(unsigned short u) {
    union { unsigned int i; float f; } v; v.i = ((unsigned int)u) << 16; return v.f;
}
__device__ __forceinline__ unsigned short f2bu(float f) {
    __hip_bfloat16 h = __float2bfloat16(f);
    return *reinterpret_cast<unsigned short*>(&h);
}

// per-row mln stats from registers: v[8] = row values at cols nf*16+l15 (16 lanes hold full row)
__device__ __forceinline__ void mln_rowstat(
    const float* v, const float* pgv, const float* pbv,
    float& m, float& rstd, float& mq)
{
    float s1 = 0.f, s2 = 0.f;
    #pragma unroll
    for (int nf = 0; nf < 8; ++nf) { s1 += v[nf]; s2 += v[nf]*v[nf]; }
    #pragma unroll
    for (int o = 1; o < 16; o <<= 1) { s1 += __shfl_xor(s1, o); s2 += __shfl_xor(s2, o); }
    m = s1 * (1.f/128.f);
    float var = s2 * (1.f/128.f) - m*m;
    rstd = rsqrtf(fmaxf(var, 0.f) + 1e-5f);
    float q = 0.f;
    #pragma unroll
    for (int nf = 0; nf < 8; ++nf) {
        float yv = (v[nf] - m) * rstd * pgv[nf] + pbv[nf];
        q += (nf < 2 ? -(yv*yv) : (yv*yv));     // cols 0..31 = "t" part (negative)
    }
    #pragma unroll
    for (int o = 1; o < 16; o <<= 1) q += __shfl_xor(q, o);
    mq = q;
}

// stage 128x128 A-tile into LDS (stride 272B) applying the mln transform from h + stats
__device__ __forceinline__ void stage_mln_tile(
    unsigned char* As, const float* __restrict__ h, int row0,
    const float* __restrict__ stats, float eps,
    const float* __restrict__ pg, const float* __restrict__ pb,
    const float* __restrict__ gg, const float* __restrict__ gb, int tid)
{
    int rbase = tid >> 4, q8 = (tid & 15) << 3;
    f4 pg0 = *(const f4*)(pg + q8), pg1 = *(const f4*)(pg + q8 + 4);
    f4 pb0 = *(const f4*)(pb + q8), pb1 = *(const f4*)(pb + q8 + 4);
    f4 gg0 = *(const f4*)(gg + q8), gg1 = *(const f4*)(gg + q8 + 4);
    f4 gb0 = *(const f4*)(gb + q8), gb1 = *(const f4*)(gb + q8 + 4);
    #pragma unroll
    for (int p = 0; p < 8; ++p) {
        int row = rbase + p*16;
        int r = row0 + row;
        float m  = stats[(size_t)r*4 + 0];
        float rs = stats[(size_t)r*4 + 1];
        float mq = stats[(size_t)r*4 + 2];
        float s3 = 1.f / (sqrtf(fabsf(mq) + eps) + eps);
        f4 x0 = *(const f4*)(h + (size_t)r*128 + q8);
        f4 x1 = *(const f4*)(h + (size_t)r*128 + q8 + 4);
        union { unsigned short u[8]; uint4 qv; } o;
        #pragma unroll
        for (int j = 0; j < 4; ++j) {
            o.u[j]   = f2bu(gg0[j] * (((x0[j]-m)*rs*pg0[j] + pb0[j]) * s3) + gb0[j]);
            o.u[j+4] = f2bu(gg1[j] * (((x1[j]-m)*rs*pg1[j] + pb1[j]) * s3) + gb1[j]);
        }
        *(uint4*)(As + row*272 + q8*2) = o.qv;
    }
}

// ---------------- pack ALL weights to bf16, transposed W^T[n][k] ----------------
__global__ __launch_bounds__(256) void pack_w_k(
    const float* __restrict__ qt, const float* __restrict__ kt,
    const float* __restrict__ qs, const float* __restrict__ ks,
    const float* __restrict__ vw, const float* __restrict__ ow,
    const float* __restrict__ w1, const float* __restrict__ w2,
    unsigned short* __restrict__ wqT, unsigned short* __restrict__ outT,
    unsigned short* __restrict__ ff1T, unsigned short* __restrict__ ff2T)
{
    int idx = blockIdx.x * 256 + threadIdx.x;          // 589824 total
    if (idx < 147456) {
        int i = idx / 49152, r = idx % 49152;
        int n = r / 128, k = r % 128;
        float v;
        if (n < 32)        v = qt[i*4096  + k*32  + n];
        else if (n < 64)   v = kt[i*4096  + k*32  + (n-32)];
        else if (n < 160)  v = qs[i*12288 + k*96  + (n-64)];
        else if (n < 256)  v = ks[i*12288 + k*96  + (n-160)];
        else               v = vw[i*16384 + k*128 + (n-256)];
        wqT[idx] = f2bu(v);
    } else if (idx < 196608) {
        int j = idx - 147456;
        int i = j / 16384, r = j % 16384;
        int n = r / 128, k = r % 128;
        outT[j] = f2bu(ow[i*16384 + k*128 + n]);
    } else if (idx < 393216) {
        int j = idx - 196608;
        int i = j / 65536, r = j % 65536;
        int n = r / 128, k = r % 128;
        ff1T[j] = f2bu(w1[i*65536 + k*512 + n]);
    } else {
        int j = idx - 393216;
        int i = j / 65536, r = j % 65536;
        int n = r / 512, k = r % 512;
        ff2T[j] = f2bu(w2[i*65536 + k*128 + n]);
    }
}

// ---------------- embedding: h = x @ embed_w + embed_b + pos ----------------
__global__ __launch_bounds__(256) void embed_k(
    const float* __restrict__ x, const float* __restrict__ ew,
    const float* __restrict__ eb, const float* __restrict__ pos,
    float* __restrict__ h)
{
    int idx = blockIdx.x * 256 + threadIdx.x;      // NTOK*128
    int n = idx >> 7, d = idx & 127;
    int t = n % TT;
    const float* xr = x + (size_t)n * 6;
    float acc = eb[d] + pos[t*128 + d];
    #pragma unroll
    for (int k = 0; k < 6; ++k) acc += xr[k] * ew[k*128 + d];
    h[idx] = acc;
}

// ---------------- mln stats (standalone — only after embed) ----------------
__global__ __launch_bounds__(256) void mln_stats_k(
    const float* __restrict__ h, const float* __restrict__ pg, const float* __restrict__ pb,
    float* __restrict__ stats, float* __restrict__ partials)
{
    int wid = threadIdx.x >> 6, lane = threadIdx.x & 63;
    int tok = blockIdx.x * 4 + wid;
    const float* hr = h + (size_t)tok * 128;
    float x0 = hr[lane], x1 = hr[lane + 64];
    float s = x0 + x1;
    #pragma unroll
    for (int o = 32; o > 0; o >>= 1) s += __shfl_xor(s, o);
    float m = s * (1.f / 128.f);
    float d0 = x0 - m, d1 = x1 - m;
    float v = d0*d0 + d1*d1;
    #pragma unroll
    for (int o = 32; o > 0; o >>= 1) v += __shfl_xor(v, o);
    float rstd = rsqrtf(v * (1.f / 128.f) + 1e-5f);
    float y0 = d0 * rstd * pg[lane]      + pb[lane];
    float y1 = d1 * rstd * pg[lane + 64] + pb[lane + 64];
    float q = (lane < 32 ? -(y0*y0) : (y0*y0)) + y1*y1;
    #pragma unroll
    for (int o = 32; o > 0; o >>= 1) q += __shfl_xor(q, o);
    if (lane == 0) {
        stats[(size_t)tok*4 + 0] = m;
        stats[(size_t)tok*4 + 1] = rstd;
        stats[(size_t)tok*4 + 2] = q;
    }
    __shared__ float pm[4];
    if (lane == 0) pm[wid] = fabsf(q);
    __syncthreads();
    if (threadIdx.x == 0) partials[blockIdx.x] = (pm[0] + pm[1]) + (pm[2] + pm[3]);
}

// ---------------- reduce partials -> eps scalar (deterministic) ----------------
__global__ __launch_bounds__(1024) void reduce_eps_k(
    const float* __restrict__ partials, int n, float* __restrict__ scal)
{
    float s = 0.f;
    for (int i = threadIdx.x; i < n; i += 1024) s += partials[i];
    __shared__ float sm[1024];
    sm[threadIdx.x] = s;
    __syncthreads();
    for (int o = 512; o > 0; o >>= 1) {
        if (threadIdx.x < o) sm[threadIdx.x] += sm[threadIdx.x + o];
        __syncthreads();
    }
    if (threadIdx.x == 0) {
        float mean = sm[0] / (float)NTOK;
        scal[0] = fmaxf(0.01f * mean, 1e-5f);
    }
}

// ---------------- apply mln (final, for head): y = g*(ln(x)*s3)+b -> bf16 ----------------
__global__ __launch_bounds__(256) void mln_apply_k(
    const float* __restrict__ h, const float* __restrict__ stats, const float* __restrict__ scal,
    const float* __restrict__ pg, const float* __restrict__ pb,
    const float* __restrict__ gg, const float* __restrict__ gb,
    unsigned short* __restrict__ y)
{
    int gid = blockIdx.x * 256 + threadIdx.x;      // NTOK*32
    int tok = gid >> 5, c4 = (gid & 31) << 2;
    float eps = scal[0];
    float m  = stats[(size_t)tok*4 + 0];
    float rs = stats[(size_t)tok*4 + 1];
    float mq = stats[(size_t)tok*4 + 2];
    float s3 = 1.f / (sqrtf(fabsf(mq) + eps) + eps);
    f4 x = *(const f4*)(h + (size_t)tok*128 + c4);
    ushort4 o;
    o.x = f2bu(gg[c4+0] * (((x[0]-m)*rs*pg[c4+0] + pb[c4+0]) * s3) + gb[c4+0]);
    o.y = f2bu(gg[c4+1] * (((x[1]-m)*rs*pg[c4+1] + pb[c4+1]) * s3) + gb[c4+1]);
    o.z = f2bu(gg[c4+2] * (((x[2]-m)*rs*pg[c4+2] + pb[c4+2]) * s3) + gb[c4+2]);
    o.w = f2bu(gg[c4+3] * (((x[3]-m)*rs*pg[c4+3] + pb[c4+3]) * s3) + gb[c4+3]);
    *(ushort4*)(y + (size_t)tok*128 + c4) = o;
}

// ---------------- 128-col-tile MFMA GEMM, B-frags from global (L2) ----------------
// AMODE 0: A = bf16 buffer (out-proj input = attn out)   AMODE 1: A = mln(h) on the fly
// EPI 0: bf16 store to obuf (no bias)  [QKV]
// EPI 2: hres += v+bias, then per-row mln stats for next norm  [out-proj]
template<int AMODE, int EPI>
__global__ __launch_bounds__(256) void gemm128_k(
    const unsigned short* __restrict__ A,     // AMODE 0
    const float* __restrict__ hsrc,           // AMODE 1
    const float* __restrict__ stats_in, const float* __restrict__ scal,
    const float* __restrict__ mg_pre_g, const float* __restrict__ mg_pre_b,
    const float* __restrict__ mg_g, const float* __restrict__ mg_b,
    const unsigned short* __restrict__ BT,
    const float* __restrict__ bias,
    unsigned short* __restrict__ obuf, int ldo,
    float* __restrict__ hres,
    const float* __restrict__ pre_g, const float* __restrict__ pre_b,
    float* __restrict__ stats, float* __restrict__ partials)
{
    __shared__ unsigned char As[128*272];
    __shared__ float sm[16];
    const int tid = threadIdx.x, wid = tid >> 6, lane = tid & 63;
    const int q = lane >> 4, l15 = lane & 15;
    const int row0 = blockIdx.y * 128, col0 = blockIdx.x * 128;
    const int wrow = wid * 32;

    if (AMODE == 0) {
        int row = tid >> 4, q8 = (tid & 15) << 3;
        #pragma unroll
        for (int p = 0; p < 8; ++p, row += 16) {
            uint4 av = *(const uint4*)(A + (size_t)(row0 + row)*128 + q8);
            *(uint4*)(As + row*272 + q8*2) = av;
        }
    } else {
        stage_mln_tile(As, hsrc, row0, stats_in, scal[0],
                       mg_pre_g, mg_pre_b, mg_g, mg_b, tid);
    }
    __syncthreads();

    f32x4 acc[2][8] = {};
    #pragma unroll
    for (int ks = 0; ks < 4; ++ks) {
        bf16x8 a[2];
        #pragma unroll
        for (int mf = 0; mf < 2; ++mf)
            a[mf] = *(const bf16x8*)(As + (wrow + mf*16 + l15)*272 + ks*64 + q*16);
        #pragma unroll
        for (int nf = 0; nf < 8; ++nf) {
            bf16x8 b = *(const bf16x8*)(BT + (size_t)(col0 + nf*16 + l15)*128 + ks*32 + q*8);
            #pragma unroll
            for (int mf = 0; mf < 2; ++mf)
                acc[mf][nf] = __builtin_amdgcn_mfma_f32_16x16x32_bf16(a[mf], b, acc[mf][nf], 0, 0, 0);
        }
    }

    if (EPI == 0) {
        #pragma unroll
        for (int mf = 0; mf < 2; ++mf)
            #pragma unroll
            for (int r = 0; r < 4; ++r) {
                int row = row0 + wrow + mf*16 + q*4 + r;
                #pragma unroll
                for (int nf = 0; nf < 8; ++nf)
                    obuf[(size_t)row*ldo + col0 + nf*16 + l15] = f2bu(acc[mf][nf][r]);
            }
    } else {
        float bv[8], pgv[8], pbv[8];
        #pragma unroll
        for (int nf = 0; nf < 8; ++nf) {
            int c = nf*16 + l15;
            bv[nf] = bias[c]; pgv[nf] = pre_g[c]; pbv[nf] = pre_b[c];
        }
        float amq = 0.f;
        #pragma unroll
        for (int mf = 0; mf < 2; ++mf) {
            #pragma unroll
            for (int r = 0; r < 4; ++r) {
                int row = row0 + wrow + mf*16 + q*4 + r;
                float* hr = hres + (size_t)row*128;
                float v[8];
                #pragma unroll
                for (int nf = 0; nf < 8; ++nf) {
                    float hv = hr[nf*16 + l15] + acc[mf][nf][r] + bv[nf];
                    hr[nf*16 + l15] = hv;
                    v[nf] = hv;
                }
                float m, rstd, mq;
                mln_rowstat(v, pgv, pbv, m, rstd, mq);
                if (l15 == 0) {
                    stats[(size_t)row*4 + 0] = m;
                    stats[(size_t)row*4 + 1] = rstd;
                    stats[(size_t)row*4 + 2] = mq;
                }
                amq += fabsf(mq);
            }
        }
        if (l15 == 0) sm[wid*4 + q] = amq;
        __syncthreads();
        if (tid == 0) {
            float s = 0.f;
            #pragma unroll
            for (int j = 0; j < 16; ++j) s += sm[j];
            partials[blockIdx.y] = s;
        }
    }
}

// ---------------- fused FFN: h += gelu(mln2(h)@W1+b1)@W2 + b2, + next mln stats ----------------
// 4 waves x 32 rows (256 threads) — proven best ILP shape
__global__ __launch_bounds__(256) void ffn_k(
    const float* __restrict__ hsrc,           // h (A source, via mln2 transform)
    const float* __restrict__ stats_in, const float* __restrict__ scal,
    const float* __restrict__ m2_pre_g, const float* __restrict__ m2_pre_b,
    const float* __restrict__ m2_g, const float* __restrict__ m2_b,
    const unsigned short* __restrict__ W1T,   // [512][128] bf16
    const float* __restrict__ b1,             // [512]
    const unsigned short* __restrict__ W2T,   // [128][512] bf16
    const float* __restrict__ b2,             // [128]
    float* __restrict__ h,                    // [NTOK][128] f32, +=
    const float* __restrict__ pre_g, const float* __restrict__ pre_b,
    float* __restrict__ stats, float* __restrict__ partials)
{
    __shared__ unsigned char As[128*272];
    __shared__ unsigned char Ps[128*144];
    __shared__ float sm[16];
    const int tid = threadIdx.x, wid = tid >> 6, lane = tid & 63;
    const int q = lane >> 4, l15 = lane & 15;
    const int row0 = blockIdx.x * 128;
    const int wrow = wid * 32;

    stage_mln_tile(As, hsrc, row0, stats_in, scal[0],
                   m2_pre_g, m2_pre_b, m2_g, m2_b, tid);
    __syncthreads();

    float b2v[8];
    #pragma unroll
    for (int nf = 0; nf < 8; ++nf) b2v[nf] = b2[nf*16 + l15];

    f32x4 acc2[2][8] = {};

    for (int c = 0; c < 8; ++c) {
        // ---- gemm1: P = mln2(h)_tile @ W1[:, 64c:64c+64] ----
        f32x4 acc1[2][4] = {};
        #pragma unroll
        for (int ks = 0; ks < 4; ++ks) {
            bf16x8 a[2];
            #pragma unroll
            for (int mf = 0; mf < 2; ++mf)
                a[mf] = *(const bf16x8*)(As + (wrow + mf*16 + l15)*272 + ks*64 + q*16);
            #pragma unroll
            for (int nf = 0; nf < 4; ++nf) {
                bf16x8 b = *(const bf16x8*)(W1T + (size_t)(c*64 + nf*16 + l15)*128 + ks*32 + q*8);
                #pragma unroll
                for (int mf = 0; mf < 2; ++mf)
                    acc1[mf][nf] = __builtin_amdgcn_mfma_f32_16x16x32_bf16(a[mf], b, acc1[mf][nf], 0, 0, 0);
            }
        }
        // ---- bias + exact gelu -> Ps (wave-private rows) ----
        #pragma unroll
        for (int nf = 0; nf < 4; ++nf) {
            float bb = b1[c*64 + nf*16 + l15];
            #pragma unroll
            for (int mf = 0; mf < 2; ++mf) {
                #pragma unroll
                for (int r = 0; r < 4; ++r) {
                    float v = acc1[mf][nf][r] + bb;
                    v = 0.5f * v * (1.f + erff(v * 0.70710678118654752f));
                    *(unsigned short*)(Ps + (wrow + mf*16 + q*4 + r)*144 + (nf*16 + l15)*2) = f2bu(v);
                }
            }
        }
        // ---- gemm2: acc2 += gelu_mid @ W2[64c:64c+64, :] ----
        #pragma unroll
        for (int ks2 = 0; ks2 < 2; ++ks2) {
            bf16x8 a2[2];
            #pragma unroll
            for (int mf = 0; mf < 2; ++mf)
                a2[mf] = *(const bf16x8*)(Ps + (wrow + mf*16 + l15)*144 + ks2*64 + q*16);
            #pragma unroll
            for (int nf = 0; nf < 8; ++nf) {
                bf16x8 b = *(const bf16x8*)(W2T + (size_t)(nf*16 + l15)*512 + c*64 + ks2*32 + q*8);
                #pragma unroll
                for (int mf = 0; mf < 2; ++mf)
                    acc2[mf][nf] = __builtin_amdgcn_mfma_f32_16x16x32_bf16(a2[mf], b, acc2[mf][nf], 0, 0, 0);
            }
        }
    }
    // ---- epilogue: h += acc2 + b2, then per-row stats for the NEXT mln ----
    float pgv[8], pbv[8];
    #pragma unroll
    for (int nf = 0; nf < 8; ++nf) { pgv[nf] = pre_g[nf*16 + l15]; pbv[nf] = pre_b[nf*16 + l15]; }
    float amq = 0.f;
    #pragma unroll
    for (int mf = 0; mf < 2; ++mf) {
        #pragma unroll
        for (int r = 0; r < 4; ++r) {
            int row = row0 + wrow + mf*16 + q*4 + r;
            float* hr = h + (size_t)row*128;
            float v[8];
            #pragma unroll
            for (int nf = 0; nf < 8; ++nf) {
                float hv = hr[nf*16 + l15] + acc2[mf][nf][r] + b2v[nf];
                hr[nf*16 + l15] = hv;
                v[nf] = hv;
            }
            float m, rstd, mq;
            mln_rowstat(v, pgv, pbv, m, rstd, mq);
            if (l15 == 0) {
                stats[(size_t)row*4 + 0] = m;
                stats[(size_t)row*4 + 1] = rstd;
                stats[(size_t)row*4 + 2] = mq;
            }
            amq += fabsf(mq);
        }
    }
    if (l15 == 0) sm[wid*4 + q] = amq;
    __syncthreads();
    if (tid == 0) {
        float s = 0.f;
        #pragma unroll
        for (int j = 0; j < 16; ++j) s += sm[j];
        partials[blockIdx.x] = s;
    }
}

// ---------------- attention: block per (chunk-local) batch, THREAD per (head, query) ----------------
__global__ __launch_bounds__(256) void attn_k(
    const unsigned short* __restrict__ qkv,
    unsigned short* __restrict__ yout,
    const float* __restrict__ wsp)
{
    __shared__ float Kl[4][40][32];
    __shared__ float Vl[4][40][32];
    int b = blockIdx.x;
    int tid = threadIdx.x;

    for (int e = tid; e < 1280; e += 256) {
        int r = e >> 3, q4 = (e & 7) << 2;
        int h = r / 40, t = r - h * 40;
        int hx = h << 2;
        const unsigned short* src = qkv + (size_t)(b*TT + t) * 384;
        int kcol = (h == 0) ? 32 : 128 + h*32;
        ushort4 uk = *(const ushort4*)(src + kcol + q4);
        ushort4 uv = *(const ushort4*)(src + 256 + h*32 + q4);
        f4 fk, fv;
        fk[0]=bf2f(uk.x); fk[1]=bf2f(uk.y); fk[2]=bf2f(uk.z); fk[3]=bf2f(uk.w);
        fv[0]=bf2f(uv.x); fv[1]=bf2f(uv.y); fv[2]=bf2f(uv.z); fv[3]=bf2f(uv.w);
        *(f4*)(&Kl[h][t][q4 ^ hx]) = fk;
        *(f4*)(&Vl[h][t][q4 ^ hx]) = fv;
    }
    __syncthreads();
    if (tid >= 160) return;

    int h = tid / 40, t = tid - h * 40;
    int hx = h << 2;
    const unsigned short* qrow = qkv + (size_t)(b*TT + t) * 384;
    int qcol = (h == 0) ? 0 : 32 + h*32;

    float q[32];
    #pragma unroll
    for (int k = 0; k < 32; k += 4) {
        ushort4 u = *(const ushort4*)(qrow + qcol + k);
        q[k]=bf2f(u.x); q[k+1]=bf2f(u.y); q[k+2]=bf2f(u.z); q[k+3]=bf2f(u.w);
    }
    const float scale = 0.17677669529663687f;   // 32^-0.5
    float wmul = scale;
    if (h == 0) wmul = -scale / (1.f + __expf(-wsp[0]));

    float sc[40];
    float mx = -1e30f;
    #pragma unroll
    for (int s = 0; s < 40; ++s) {
        float dot = 0.f;
        #pragma unroll
        for (int k = 0; k < 32; k += 4) {
            const f4 kv = *(const f4*)(&Kl[h][s][k ^ hx]);
            dot += q[k]*kv[0] + q[k+1]*kv[1] + q[k+2]*kv[2] + q[k+3]*kv[3];
        }
        float v = wmul * dot;
        sc[s] = v;
        mx = fmaxf(mx, v);
    }
    float sum = 0.f;
    #pragma unroll
    for (int s = 0; s < 40; ++s) { float p = __expf(sc[s] - mx); sc[s] = p; sum += p; }
    float inv = 1.f / sum;

    float acc[32] = {};
    #pragma unroll
    for (int s = 0; s < 40; ++s) {
        float p = sc[s];
        #pragma unroll
        for (int k = 0; k < 32; k += 4) {
            const f4 vv = *(const f4*)(&Vl[h][s][k ^ hx]);
            acc[k]   += p*vv[0]; acc[k+1] += p*vv[1];
            acc[k+2] += p*vv[2]; acc[k+3] += p*vv[3];
        }
    }
    unsigned short* orow = yout + (size_t)(b*TT + t) * 128 + h*32;
    #pragma unroll
    for (int k = 0; k < 32; k += 4) {
        ushort4 u;
        u.x = f2bu(acc[k]  *inv); u.y = f2bu(acc[k+1]*inv);
        u.z = f2bu(acc[k+2]*inv); u.w = f2bu(acc[k+3]*inv);
        *(ushort4*)(orow + k) = u;
    }
}

// ---------------- head: last token y (bf16) @ traj_w + traj_b (f32 out) ----------------
__global__ __launch_bounds__(128) void head_k(
    const unsigned short* __restrict__ y,
    const float* __restrict__ tw, const float* __restrict__ tb,
    float* __restrict__ out)
{
    int b = blockIdx.x, tid = threadIdx.x;
    int tok = b*TT + (TT - 1);
    __shared__ float ys[128];
    ys[tid] = bf2f(y[(size_t)tok*128 + tid]);
    __syncthreads();
    if (tid < 120) {
        float acc = tb[tid];
        #pragma unroll 4
        for (int d = 0; d < 128; ++d) acc += ys[d] * tw[d*120 + tid];
        out[(size_t)b*120 + tid] = acc;
    }
}

extern "C" void kernel_launch(void* const* d_in, const int* in_sizes, int n_in,
                              void* d_out, int out_size, void* d_ws, size_t ws_size,
                              hipStream_t stream) {
    const float* x        = (const float*)d_in[0];
    const float* embed_w  = (const float*)d_in[1];
    const float* embed_b  = (const float*)d_in[2];
    const float* pos      = (const float*)d_in[3];
    const float* qt_w     = (const float*)d_in[4];
    const float* kt_w     = (const float*)d_in[5];
    const float* qs_w     = (const float*)d_in[6];
    const float* ks_w     = (const float*)d_in[7];
    const float* v_w      = (const float*)d_in[8];
    const float* out_w    = (const float*)d_in[9];
    const float* out_b    = (const float*)d_in[10];
    const float* w_sigma  = (const float*)d_in[11];
    const float* n1_pre_g = (const float*)d_in[12];
    const float* n1_pre_b = (const float*)d_in[13];
    const float* n1_g     = (const float*)d_in[14];
    const float* n1_b     = (const float*)d_in[15];
    const float* n2_pre_g = (const float*)d_in[16];
    const float* n2_pre_b = (const float*)d_in[17];
    const float* n2_g     = (const float*)d_in[18];
    const float* n2_b     = (const float*)d_in[19];
    const float* ff_w1    = (const float*)d_in[20];
    const float* ff_b1    = (const float*)d_in[21];
    const float* ff_w2    = (const float*)d_in[22];
    const float* ff_b2    = (const float*)d_in[23];
    const float* fn_pre_g = (const float*)d_in[24];
    const float* fn_pre_b = (const float*)d_in[25];
    const float* fn_g     = (const float*)d_in[26];
    const float* fn_b     = (const float*)d_in[27];
    const float* traj_w   = (const float*)d_in[28];
    const float* traj_b   = (const float*)d_in[29];

    // ---- workspace layout (total ~192.7 MB) ----
    char* ws = (char*)d_ws;
    float*          h       = (float*)ws;                           //  83,886,080 B
    float*          stats   = (float*)(ws + 83886080);              //   2,621,440 B
    unsigned short* y       = (unsigned short*)(ws + 86507520);     //  41,943,040 B (NTOK x 128 bf16)
    unsigned short* scratch = (unsigned short*)(ws + 128450560);    //  62,914,560 B (CHTOK x 384 bf16)
    unsigned short* wqT     = (unsigned short*)(ws + 191365120);    //     294,912 B
    unsigned short* outT    = (unsigned short*)(ws + 191660032);    //      98,304 B
    unsigned short* ff1T    = (unsigned short*)(ws + 191758336);    //     393,216 B
    unsigned short* ff2T    = (unsigned short*)(ws + 192151552);    //     393,216 B
    float*          partials= (float*)(ws + 192544768);             //     163,840 B
    float*          scal    = (float*)(ws + 192708608);             //         256 B

    pack_w_k<<<2304, 256, 0, stream>>>(qt_w, kt_w, qs_w, ks_w, v_w, out_w, ff_w1, ff_w2,
                                       wqT, outT, ff1T, ff2T);
    embed_k<<<81920, 256, 0, stream>>>(x, embed_w, embed_b, pos, h);

    // stats for mln1 of layer 0 (only standalone stats pass)
    mln_stats_k<<<40960, 256, 0, stream>>>(h, n1_pre_g, n1_pre_b, stats, partials);
    reduce_eps_k<<<1, 1024, 0, stream>>>(partials, 40960, scal);

    for (int i = 0; i < NLAY; ++i) {
        for (int c = 0; c < 2; ++c) {
            size_t off = (size_t)c * CHTOK;
            // QKV with fused mln1 transform
            gemm128_k<1,0><<<dim3(3, 640), 256, 0, stream>>>(
                nullptr, h + off*128, stats + off*4, scal,
                n1_pre_g + i*128, n1_pre_b + i*128, n1_g + i*128, n1_b + i*128,
                wqT + (size_t)i*49152, nullptr, scratch, 384,
                nullptr, nullptr, nullptr, nullptr, nullptr);
            attn_k<<<2048, 256, 0, stream>>>(scratch, y + off*128, w_sigma + i);
            // out-proj: h += , stats for mln2
            gemm128_k<0,2><<<dim3(1, 640), 256, 0, stream>>>(
                y + off*128, nullptr, nullptr, nullptr,
                nullptr, nullptr, nullptr, nullptr,
                outT + (size_t)i*16384, out_b + i*128, nullptr, 0,
                h + off*128, n2_pre_g + i*128, n2_pre_b + i*128,
                stats + off*4, partials + c*640);
        }
        reduce_eps_k<<<1, 1024, 0, stream>>>(partials, 1280, scal);
        // fused FFN with mln2 transform; stats for next mln1 / final fn
        const float* npg = (i < NLAY-1) ? (n1_pre_g + (i+1)*128) : fn_pre_g;
        const float* npb = (i < NLAY-1) ? (n1_pre_b + (i+1)*128) : fn_pre_b;
        ffn_k<<<1280, 256, 0, stream>>>(
            h, stats, scal,
            n2_pre_g + i*128, n2_pre_b + i*128, n2_g + i*128, n2_b + i*128,
            ff1T + (size_t)i*65536, ff_b1 + i*512,
            ff2T + (size_t)i*65536, ff_b2 + i*128, h,
            npg, npb, stats, partials);
        reduce_eps_k<<<1, 1024, 0, stream>>>(partials, 1280, scal);
    }

    // ---- final mln apply + head ----
    mln_apply_k<<<20480, 256, 0, stream>>>(h, stats, scal, fn_pre_g, fn_pre_b, fn_g, fn_b, y);
    head_k<<<4096, 128, 0, stream>>>(y, traj_w, traj_b, (float*)d_out);
}

// Round 10
// 1669.493 us; speedup vs baseline: 1.1904x; 1.0546x over previous
//
#include <hip/hip_runtime.h>
#include <hip/hip_bf16.h>

// Model dims (fixed)
#define DIMM 128
#define TT   40
#define BB   4096
#define NTOK (BB*TT)           // 163840
#define CHTOK (NTOK/2)         // 81920 tokens per chunk (qkv scratch)
#define NLAY 3

typedef float f4 __attribute__((ext_vector_type(4)));
typedef float f32x4 __attribute__((ext_vector_type(4)));
typedef short bf16x8 __attribute__((ext_vector_type(8)));

__device__ __forceinline__ float bf2f(unsigned short u) {
    union { unsigned int i; float f; } v; v.i = ((unsigned int)u) << 16; return v.f;
}
__device__ __forceinline__ unsigned short f2bu(float f) {
    __hip_bfloat16 h = __float2bfloat16(f);
    return *reinterpret_cast<unsigned short*>(&h);
}
// tanh-form gelu via sigmoid: x * sigma(2*sqrt(2/pi)*(x+0.044715x^3))
// (error vs exact-erf gelu <= ~3e-4, far below the bf16 mid quantization already present)
__device__ __forceinline__ float gelu_f(float v) {
    float z = 1.5957691216057308f * fmaf(0.044715f * v * v, v, v);
    return v / (1.f + __expf(-z));
}

// per-row mln stats from registers: v[8] = row values at cols nf*16+l15 (16 lanes hold full row)
__device__ __forceinline__ void mln_rowstat(
    const float* v, const float* pgv, const float* pbv,
    float& m, float& rstd, float& mq)
{
    float s1 = 0.f, s2 = 0.f;
    #pragma unroll
    for (int nf = 0; nf < 8; ++nf) { s1 += v[nf]; s2 += v[nf]*v[nf]; }
    #pragma unroll
    for (int o = 1; o < 16; o <<= 1) { s1 += __shfl_xor(s1, o); s2 += __shfl_xor(s2, o); }
    m = s1 * (1.f/128.f);
    float var = s2 * (1.f/128.f) - m*m;
    rstd = rsqrtf(fmaxf(var, 0.f) + 1e-5f);
    float q = 0.f;
    #pragma unroll
    for (int nf = 0; nf < 8; ++nf) {
        float yv = (v[nf] - m) * rstd * pgv[nf] + pbv[nf];
        q += (nf < 2 ? -(yv*yv) : (yv*yv));     // cols 0..31 = "t" part (negative)
    }
    #pragma unroll
    for (int o = 1; o < 16; o <<= 1) q += __shfl_xor(q, o);
    mq = q;
}

// stage 128x128 A-tile into LDS (stride 272B) applying the mln transform from h + stats
// folded form: val = alpha[c]*t + (beta[c]*s3 + gb[c]),  t = (x - m)*rs*s3
__device__ __forceinline__ void stage_mln_tile(
    unsigned char* As, const float* __restrict__ h, int row0,
    const float* __restrict__ stats, float eps,
    const float* __restrict__ pg, const float* __restrict__ pb,
    const float* __restrict__ gg, const float* __restrict__ gb, int tid)
{
    int rbase = tid >> 4, q8 = (tid & 15) << 3;
    float al[8], be[8], gbv[8];
    #pragma unroll
    for (int j = 0; j < 8; ++j) {
        float g = gg[q8+j];
        al[j]  = g * pg[q8+j];
        be[j]  = g * pb[q8+j];
        gbv[j] = gb[q8+j];
    }
    #pragma unroll
    for (int p = 0; p < 8; ++p) {
        int row = rbase + p*16;
        int r = row0 + row;
        float m  = stats[(size_t)r*4 + 0];
        float rs = stats[(size_t)r*4 + 1];
        float mq = stats[(size_t)r*4 + 2];
        float s3 = 1.f / (sqrtf(fabsf(mq) + eps) + eps);
        float rss3 = rs * s3;
        float mm = -m * rss3;
        f4 x0 = *(const f4*)(h + (size_t)r*128 + q8);
        f4 x1 = *(const f4*)(h + (size_t)r*128 + q8 + 4);
        union { unsigned short u[8]; uint4 qv; } o;
        #pragma unroll
        for (int j = 0; j < 4; ++j) {
            float t0 = fmaf(x0[j], rss3, mm);
            float t1 = fmaf(x1[j], rss3, mm);
            o.u[j]   = f2bu(fmaf(al[j],   t0, fmaf(be[j],   s3, gbv[j])));
            o.u[j+4] = f2bu(fmaf(al[j+4], t1, fmaf(be[j+4], s3, gbv[j+4])));
        }
        *(uint4*)(As + row*272 + q8*2) = o.qv;
    }
}

// ---------------- pack ALL weights to bf16, transposed W^T[n][k] ----------------
__global__ __launch_bounds__(256) void pack_w_k(
    const float* __restrict__ qt, const float* __restrict__ kt,
    const float* __restrict__ qs, const float* __restrict__ ks,
    const float* __restrict__ vw, const float* __restrict__ ow,
    const float* __restrict__ w1, const float* __restrict__ w2,
    unsigned short* __restrict__ wqT, unsigned short* __restrict__ outT,
    unsigned short* __restrict__ ff1T, unsigned short* __restrict__ ff2T)
{
    int idx = blockIdx.x * 256 + threadIdx.x;          // 589824 total
    if (idx < 147456) {
        int i = idx / 49152, r = idx % 49152;
        int n = r / 128, k = r % 128;
        float v;
        if (n < 32)        v = qt[i*4096  + k*32  + n];
        else if (n < 64)   v = kt[i*4096  + k*32  + (n-32)];
        else if (n < 160)  v = qs[i*12288 + k*96  + (n-64)];
        else if (n < 256)  v = ks[i*12288 + k*96  + (n-160)];
        else               v = vw[i*16384 + k*128 + (n-256)];
        wqT[idx] = f2bu(v);
    } else if (idx < 196608) {
        int j = idx - 147456;
        int i = j / 16384, r = j % 16384;
        int n = r / 128, k = r % 128;
        outT[j] = f2bu(ow[i*16384 + k*128 + n]);
    } else if (idx < 393216) {
        int j = idx - 196608;
        int i = j / 65536, r = j % 65536;
        int n = r / 128, k = r % 128;
        ff1T[j] = f2bu(w1[i*65536 + k*512 + n]);
    } else {
        int j = idx - 393216;
        int i = j / 65536, r = j % 65536;
        int n = r / 512, k = r % 512;
        ff2T[j] = f2bu(w2[i*65536 + k*128 + n]);
    }
}

// ---------------- embedding: h = x @ embed_w + embed_b + pos ----------------
__global__ __launch_bounds__(256) void embed_k(
    const float* __restrict__ x, const float* __restrict__ ew,
    const float* __restrict__ eb, const float* __restrict__ pos,
    float* __restrict__ h)
{
    int idx = blockIdx.x * 256 + threadIdx.x;      // NTOK*128
    int n = idx >> 7, d = idx & 127;
    int t = n % TT;
    const float* xr = x + (size_t)n * 6;
    float acc = eb[d] + pos[t*128 + d];
    #pragma unroll
    for (int k = 0; k < 6; ++k) acc += xr[k] * ew[k*128 + d];
    h[idx] = acc;
}

// ---------------- mln stats (standalone — only after embed) ----------------
__global__ __launch_bounds__(256) void mln_stats_k(
    const float* __restrict__ h, const float* __restrict__ pg, const float* __restrict__ pb,
    float* __restrict__ stats, float* __restrict__ partials)
{
    int wid = threadIdx.x >> 6, lane = threadIdx.x & 63;
    int tok = blockIdx.x * 4 + wid;
    const float* hr = h + (size_t)tok * 128;
    float x0 = hr[lane], x1 = hr[lane + 64];
    float s = x0 + x1;
    #pragma unroll
    for (int o = 32; o > 0; o >>= 1) s += __shfl_xor(s, o);
    float m = s * (1.f / 128.f);
    float d0 = x0 - m, d1 = x1 - m;
    float v = d0*d0 + d1*d1;
    #pragma unroll
    for (int o = 32; o > 0; o >>= 1) v += __shfl_xor(v, o);
    float rstd = rsqrtf(v * (1.f / 128.f) + 1e-5f);
    float y0 = d0 * rstd * pg[lane]      + pb[lane];
    float y1 = d1 * rstd * pg[lane + 64] + pb[lane + 64];
    float q = (lane < 32 ? -(y0*y0) : (y0*y0)) + y1*y1;
    #pragma unroll
    for (int o = 32; o > 0; o >>= 1) q += __shfl_xor(q, o);
    if (lane == 0) {
        stats[(size_t)tok*4 + 0] = m;
        stats[(size_t)tok*4 + 1] = rstd;
        stats[(size_t)tok*4 + 2] = q;
    }
    __shared__ float pm[4];
    if (lane == 0) pm[wid] = fabsf(q);
    __syncthreads();
    if (threadIdx.x == 0) partials[blockIdx.x] = (pm[0] + pm[1]) + (pm[2] + pm[3]);
}

// ---------------- reduce partials -> eps scalar (deterministic) ----------------
__global__ __launch_bounds__(1024) void reduce_eps_k(
    const float* __restrict__ partials, int n, float* __restrict__ scal)
{
    float s = 0.f;
    for (int i = threadIdx.x; i < n; i += 1024) s += partials[i];
    __shared__ float sm[1024];
    sm[threadIdx.x] = s;
    __syncthreads();
    for (int o = 512; o > 0; o >>= 1) {
        if (threadIdx.x < o) sm[threadIdx.x] += sm[threadIdx.x + o];
        __syncthreads();
    }
    if (threadIdx.x == 0) {
        float mean = sm[0] / (float)NTOK;
        scal[0] = fmaxf(0.01f * mean, 1e-5f);
    }
}

// ---------------- apply mln (final, for head): y = g*(ln(x)*s3)+b -> bf16 ----------------
__global__ __launch_bounds__(256) void mln_apply_k(
    const float* __restrict__ h, const float* __restrict__ stats, const float* __restrict__ scal,
    const float* __restrict__ pg, const float* __restrict__ pb,
    const float* __restrict__ gg, const float* __restrict__ gb,
    unsigned short* __restrict__ y)
{
    int gid = blockIdx.x * 256 + threadIdx.x;      // NTOK*32
    int tok = gid >> 5, c4 = (gid & 31) << 2;
    float eps = scal[0];
    float m  = stats[(size_t)tok*4 + 0];
    float rs = stats[(size_t)tok*4 + 1];
    float mq = stats[(size_t)tok*4 + 2];
    float s3 = 1.f / (sqrtf(fabsf(mq) + eps) + eps);
    f4 x = *(const f4*)(h + (size_t)tok*128 + c4);
    ushort4 o;
    o.x = f2bu(gg[c4+0] * (((x[0]-m)*rs*pg[c4+0] + pb[c4+0]) * s3) + gb[c4+0]);
    o.y = f2bu(gg[c4+1] * (((x[1]-m)*rs*pg[c4+1] + pb[c4+1]) * s3) + gb[c4+1]);
    o.z = f2bu(gg[c4+2] * (((x[2]-m)*rs*pg[c4+2] + pb[c4+2]) * s3) + gb[c4+2]);
    o.w = f2bu(gg[c4+3] * (((x[3]-m)*rs*pg[c4+3] + pb[c4+3]) * s3) + gb[c4+3]);
    *(ushort4*)(y + (size_t)tok*128 + c4) = o;
}

// ---------------- QKV GEMM: scratch = mln1(h) @ Wq  (N=384 looped in 3x128) ----------------
// one block = 128 rows; A-tile transformed+staged ONCE, frags held in registers
__global__ __launch_bounds__(256) void qkv_k(
    const float* __restrict__ hsrc,
    const float* __restrict__ stats_in, const float* __restrict__ scal,
    const float* __restrict__ pg, const float* __restrict__ pb,
    const float* __restrict__ gg, const float* __restrict__ gb,
    const unsigned short* __restrict__ BT,    // [384][128] bf16
    unsigned short* __restrict__ obuf)        // [rows][384] bf16
{
    __shared__ unsigned char As[128*272];
    const int tid = threadIdx.x, wid = tid >> 6, lane = tid & 63;
    const int q = lane >> 4, l15 = lane & 15;
    const int row0 = blockIdx.x * 128;
    const int wrow = wid * 32;

    stage_mln_tile(As, hsrc, row0, stats_in, scal[0], pg, pb, gg, gb, tid);
    __syncthreads();

    bf16x8 a[2][4];
    #pragma unroll
    for (int mf = 0; mf < 2; ++mf)
        #pragma unroll
        for (int ks = 0; ks < 4; ++ks)
            a[mf][ks] = *(const bf16x8*)(As + (wrow + mf*16 + l15)*272 + ks*64 + q*16);

    for (int nc = 0; nc < 3; ++nc) {
        f32x4 acc[2][8] = {};
        #pragma unroll
        for (int ks = 0; ks < 4; ++ks)
            #pragma unroll
            for (int nf = 0; nf < 8; ++nf) {
                bf16x8 b = *(const bf16x8*)(BT + (size_t)(nc*128 + nf*16 + l15)*128 + ks*32 + q*8);
                #pragma unroll
                for (int mf = 0; mf < 2; ++mf)
                    acc[mf][nf] = __builtin_amdgcn_mfma_f32_16x16x32_bf16(a[mf][ks], b, acc[mf][nf], 0, 0, 0);
            }
        #pragma unroll
        for (int mf = 0; mf < 2; ++mf)
            #pragma unroll
            for (int r = 0; r < 4; ++r) {
                int row = row0 + wrow + mf*16 + q*4 + r;
                #pragma unroll
                for (int nf = 0; nf < 8; ++nf)
                    obuf[(size_t)row*384 + nc*128 + nf*16 + l15] = f2bu(acc[mf][nf][r]);
            }
    }
}

// ---------------- out-proj GEMM: h += y @ Wout + b, then mln2 stats; NO LDS staging ----------------
__global__ __launch_bounds__(256) void outproj_k(
    const unsigned short* __restrict__ A,     // y chunk [rows][128] bf16
    const unsigned short* __restrict__ BT,    // [128][128] bf16
    const float* __restrict__ bias,
    float* __restrict__ hres,
    const float* __restrict__ pre_g, const float* __restrict__ pre_b,
    float* __restrict__ stats, float* __restrict__ partials)
{
    __shared__ float sm[16];
    const int tid = threadIdx.x, wid = tid >> 6, lane = tid & 63;
    const int q = lane >> 4, l15 = lane & 15;
    const int row0 = blockIdx.x * 128;
    const int wrow = wid * 32;

    bf16x8 a[2][4];
    #pragma unroll
    for (int mf = 0; mf < 2; ++mf) {
        int row = row0 + wrow + mf*16 + l15;
        #pragma unroll
        for (int ks = 0; ks < 4; ++ks)
            a[mf][ks] = *(const bf16x8*)(A + (size_t)row*128 + ks*32 + q*8);
    }

    f32x4 acc[2][8] = {};
    #pragma unroll
    for (int ks = 0; ks < 4; ++ks)
        #pragma unroll
        for (int nf = 0; nf < 8; ++nf) {
            bf16x8 b = *(const bf16x8*)(BT + (size_t)(nf*16 + l15)*128 + ks*32 + q*8);
            #pragma unroll
            for (int mf = 0; mf < 2; ++mf)
                acc[mf][nf] = __builtin_amdgcn_mfma_f32_16x16x32_bf16(a[mf][ks], b, acc[mf][nf], 0, 0, 0);
        }

    float bv[8], pgv[8], pbv[8];
    #pragma unroll
    for (int nf = 0; nf < 8; ++nf) {
        int c = nf*16 + l15;
        bv[nf] = bias[c]; pgv[nf] = pre_g[c]; pbv[nf] = pre_b[c];
    }
    float amq = 0.f;
    #pragma unroll
    for (int mf = 0; mf < 2; ++mf) {
        #pragma unroll
        for (int r = 0; r < 4; ++r) {
            int row = row0 + wrow + mf*16 + q*4 + r;
            float* hr = hres + (size_t)row*128;
            float v[8];
            #pragma unroll
            for (int nf = 0; nf < 8; ++nf) {
                float hv = hr[nf*16 + l15] + acc[mf][nf][r] + bv[nf];
                hr[nf*16 + l15] = hv;
                v[nf] = hv;
            }
            float m, rstd, mq;
            mln_rowstat(v, pgv, pbv, m, rstd, mq);
            if (l15 == 0) {
                stats[(size_t)row*4 + 0] = m;
                stats[(size_t)row*4 + 1] = rstd;
                stats[(size_t)row*4 + 2] = mq;
            }
            amq += fabsf(mq);
        }
    }
    if (l15 == 0) sm[wid*4 + q] = amq;
    __syncthreads();
    if (tid == 0) {
        float s = 0.f;
        #pragma unroll
        for (int j = 0; j < 16; ++j) s += sm[j];
        partials[blockIdx.x] = s;
    }
}

// ---------------- fused FFN: h += gelu(mln2(h)@W1+b1)@W2 + b2, + next mln stats ----------------
__global__ __launch_bounds__(256) void ffn_k(
    const float* __restrict__ hsrc,
    const float* __restrict__ stats_in, const float* __restrict__ scal,
    const float* __restrict__ m2_pre_g, const float* __restrict__ m2_pre_b,
    const float* __restrict__ m2_g, const float* __restrict__ m2_b,
    const unsigned short* __restrict__ W1T,   // [512][128] bf16
    const float* __restrict__ b1,             // [512]
    const unsigned short* __restrict__ W2T,   // [128][512] bf16
    const float* __restrict__ b2,             // [128]
    float* __restrict__ h,                    // [NTOK][128] f32, +=
    const float* __restrict__ pre_g, const float* __restrict__ pre_b,
    float* __restrict__ stats, float* __restrict__ partials)
{
    __shared__ unsigned char As[128*272];
    __shared__ unsigned char Ps[128*144];
    __shared__ float sm[16];
    const int tid = threadIdx.x, wid = tid >> 6, lane = tid & 63;
    const int q = lane >> 4, l15 = lane & 15;
    const int row0 = blockIdx.x * 128;
    const int wrow = wid * 32;

    stage_mln_tile(As, hsrc, row0, stats_in, scal[0],
                   m2_pre_g, m2_pre_b, m2_g, m2_b, tid);
    __syncthreads();

    // hoist A fragments to registers (reused across all 8 c-chunks)
    bf16x8 a[2][4];
    #pragma unroll
    for (int mf = 0; mf < 2; ++mf)
        #pragma unroll
        for (int ks = 0; ks < 4; ++ks)
            a[mf][ks] = *(const bf16x8*)(As + (wrow + mf*16 + l15)*272 + ks*64 + q*16);

    float b2v[8];
    #pragma unroll
    for (int nf = 0; nf < 8; ++nf) b2v[nf] = b2[nf*16 + l15];

    f32x4 acc2[2][8] = {};

    for (int c = 0; c < 8; ++c) {
        // ---- gemm1: P = mln2(h)_tile @ W1[:, 64c:64c+64] ----
        f32x4 acc1[2][4] = {};
        #pragma unroll
        for (int ks = 0; ks < 4; ++ks)
            #pragma unroll
            for (int nf = 0; nf < 4; ++nf) {
                bf16x8 b = *(const bf16x8*)(W1T + (size_t)(c*64 + nf*16 + l15)*128 + ks*32 + q*8);
                #pragma unroll
                for (int mf = 0; mf < 2; ++mf)
                    acc1[mf][nf] = __builtin_amdgcn_mfma_f32_16x16x32_bf16(a[mf][ks], b, acc1[mf][nf], 0, 0, 0);
            }
        // ---- bias + gelu -> Ps (wave-private rows) ----
        #pragma unroll
        for (int nf = 0; nf < 4; ++nf) {
            float bb = b1[c*64 + nf*16 + l15];
            #pragma unroll
            for (int mf = 0; mf < 2; ++mf) {
                #pragma unroll
                for (int r = 0; r < 4; ++r) {
                    float v = gelu_f(acc1[mf][nf][r] + bb);
                    *(unsigned short*)(Ps + (wrow + mf*16 + q*4 + r)*144 + (nf*16 + l15)*2) = f2bu(v);
                }
            }
        }
        // ---- gemm2: acc2 += gelu_mid @ W2[64c:64c+64, :] ----
        #pragma unroll
        for (int ks2 = 0; ks2 < 2; ++ks2) {
            bf16x8 a2[2];
            #pragma unroll
            for (int mf = 0; mf < 2; ++mf)
                a2[mf] = *(const bf16x8*)(Ps + (wrow + mf*16 + l15)*144 + ks2*64 + q*16);
            #pragma unroll
            for (int nf = 0; nf < 8; ++nf) {
                bf16x8 b = *(const bf16x8*)(W2T + (size_t)(nf*16 + l15)*512 + c*64 + ks2*32 + q*8);
                #pragma unroll
                for (int mf = 0; mf < 2; ++mf)
                    acc2[mf][nf] = __builtin_amdgcn_mfma_f32_16x16x32_bf16(a2[mf], b, acc2[mf][nf], 0, 0, 0);
            }
        }
    }
    // ---- epilogue: h += acc2 + b2, then per-row stats for the NEXT mln ----
    float pgv[8], pbv[8];
    #pragma unroll
    for (int nf = 0; nf < 8; ++nf) { pgv[nf] = pre_g[nf*16 + l15]; pbv[nf] = pre_b[nf*16 + l15]; }
    float amq = 0.f;
    #pragma unroll
    for (int mf = 0; mf < 2; ++mf) {
        #pragma unroll
        for (int r = 0; r < 4; ++r) {
            int row = row0 + wrow + mf*16 + q*4 + r;
            float* hr = h + (size_t)row*128;
            float v[8];
            #pragma unroll
            for (int nf = 0; nf < 8; ++nf) {
                float hv = hr[nf*16 + l15] + acc2[mf][nf][r] + b2v[nf];
                hr[nf*16 + l15] = hv;
                v[nf] = hv;
            }
            float m, rstd, mq;
            mln_rowstat(v, pgv, pbv, m, rstd, mq);
            if (l15 == 0) {
                stats[(size_t)row*4 + 0] = m;
                stats[(size_t)row*4 + 1] = rstd;
                stats[(size_t)row*4 + 2] = mq;
            }
            amq += fabsf(mq);
        }
    }
    if (l15 == 0) sm[wid*4 + q] = amq;
    __syncthreads();
    if (tid == 0) {
        float s = 0.f;
        #pragma unroll
        for (int j = 0; j < 16; ++j) s += sm[j];
        partials[blockIdx.x] = s;
    }
}

// ---------------- attention: block per (chunk-local) batch, THREAD per (head, query) ----------------
__global__ __launch_bounds__(256) void attn_k(
    const unsigned short* __restrict__ qkv,
    unsigned short* __restrict__ yout,
    const float* __restrict__ wsp)
{
    __shared__ float Kl[4][40][32];
    __shared__ float Vl[4][40][32];
    int b = blockIdx.x;
    int tid = threadIdx.x;

    for (int e = tid; e < 1280; e += 256) {
        int r = e >> 3, q4 = (e & 7) << 2;
        int h = r / 40, t = r - h * 40;
        int hx = h << 2;
        const unsigned short* src = qkv + (size_t)(b*TT + t) * 384;
        int kcol = (h == 0) ? 32 : 128 + h*32;
        ushort4 uk = *(const ushort4*)(src + kcol + q4);
        ushort4 uv = *(const ushort4*)(src + 256 + h*32 + q4);
        f4 fk, fv;
        fk[0]=bf2f(uk.x); fk[1]=bf2f(uk.y); fk[2]=bf2f(uk.z); fk[3]=bf2f(uk.w);
        fv[0]=bf2f(uv.x); fv[1]=bf2f(uv.y); fv[2]=bf2f(uv.z); fv[3]=bf2f(uv.w);
        *(f4*)(&Kl[h][t][q4 ^ hx]) = fk;
        *(f4*)(&Vl[h][t][q4 ^ hx]) = fv;
    }
    __syncthreads();
    if (tid >= 160) return;

    int h = tid / 40, t = tid - h * 40;
    int hx = h << 2;
    const unsigned short* qrow = qkv + (size_t)(b*TT + t) * 384;
    int qcol = (h == 0) ? 0 : 32 + h*32;

    float q[32];
    #pragma unroll
    for (int k = 0; k < 32; k += 4) {
        ushort4 u = *(const ushort4*)(qrow + qcol + k);
        q[k]=bf2f(u.x); q[k+1]=bf2f(u.y); q[k+2]=bf2f(u.z); q[k+3]=bf2f(u.w);
    }
    const float scale = 0.17677669529663687f;   // 32^-0.5
    float wmul = scale;
    if (h == 0) wmul = -scale / (1.f + __expf(-wsp[0]));

    float sc[40];
    float mx = -1e30f;
    #pragma unroll
    for (int s = 0; s < 40; ++s) {
        float dot = 0.f;
        #pragma unroll
        for (int k = 0; k < 32; k += 4) {
            const f4 kv = *(const f4*)(&Kl[h][s][k ^ hx]);
            dot += q[k]*kv[0] + q[k+1]*kv[1] + q[k+2]*kv[2] + q[k+3]*kv[3];
        }
        float v = wmul * dot;
        sc[s] = v;
        mx = fmaxf(mx, v);
    }
    float sum = 0.f;
    #pragma unroll
    for (int s = 0; s < 40; ++s) { float p = __expf(sc[s] - mx); sc[s] = p; sum += p; }
    float inv = 1.f / sum;

    float acc[32] = {};
    #pragma unroll
    for (int s = 0; s < 40; ++s) {
        float p = sc[s];
        #pragma unroll
        for (int k = 0; k < 32; k += 4) {
            const f4 vv = *(const f4*)(&Vl[h][s][k ^ hx]);
            acc[k]   += p*vv[0]; acc[k+1] += p*vv[1];
            acc[k+2] += p*vv[2]; acc[k+3] += p*vv[3];
        }
    }
    unsigned short* orow = yout + (size_t)(b*TT + t) * 128 + h*32;
    #pragma unroll
    for (int k = 0; k < 32; k += 4) {
        ushort4 u;
        u.x = f2bu(acc[k]  *inv); u.y = f2bu(acc[k+1]*inv);
        u.z = f2bu(acc[k+2]*inv); u.w = f2bu(acc[k+3]*inv);
        *(ushort4*)(orow + k) = u;
    }
}

// ---------------- head: last token y (bf16) @ traj_w + traj_b (f32 out) ----------------
__global__ __launch_bounds__(128) void head_k(
    const unsigned short* __restrict__ y,
    const float* __restrict__ tw, const float* __restrict__ tb,
    float* __restrict__ out)
{
    int b = blockIdx.x, tid = threadIdx.x;
    int tok = b*TT + (TT - 1);
    __shared__ float ys[128];
    ys[tid] = bf2f(y[(size_t)tok*128 + tid]);
    __syncthreads();
    if (tid < 120) {
        float acc = tb[tid];
        #pragma unroll 4
        for (int d = 0; d < 128; ++d) acc += ys[d] * tw[d*120 + tid];
        out[(size_t)b*120 + tid] = acc;
    }
}

extern "C" void kernel_launch(void* const* d_in, const int* in_sizes, int n_in,
                              void* d_out, int out_size, void* d_ws, size_t ws_size,
                              hipStream_t stream) {
    const float* x        = (const float*)d_in[0];
    const float* embed_w  = (const float*)d_in[1];
    const float* embed_b  = (const float*)d_in[2];
    const float* pos      = (const float*)d_in[3];
    const float* qt_w     = (const float*)d_in[4];
    const float* kt_w     = (const float*)d_in[5];
    const float* qs_w     = (const float*)d_in[6];
    const float* ks_w     = (const float*)d_in[7];
    const float* v_w      = (const float*)d_in[8];
    const float* out_w    = (const float*)d_in[9];
    const float* out_b    = (const float*)d_in[10];
    const float* w_sigma  = (const float*)d_in[11];
    const float* n1_pre_g = (const float*)d_in[12];
    const float* n1_pre_b = (const float*)d_in[13];
    const float* n1_g     = (const float*)d_in[14];
    const float* n1_b     = (const float*)d_in[15];
    const float* n2_pre_g = (const float*)d_in[16];
    const float* n2_pre_b = (const float*)d_in[17];
    const float* n2_g     = (const float*)d_in[18];
    const float* n2_b     = (const float*)d_in[19];
    const float* ff_w1    = (const float*)d_in[20];
    const float* ff_b1    = (const float*)d_in[21];
    const float* ff_w2    = (const float*)d_in[22];
    const float* ff_b2    = (const float*)d_in[23];
    const float* fn_pre_g = (const float*)d_in[24];
    const float* fn_pre_b = (const float*)d_in[25];
    const float* fn_g     = (const float*)d_in[26];
    const float* fn_b     = (const float*)d_in[27];
    const float* traj_w   = (const float*)d_in[28];
    const float* traj_b   = (const float*)d_in[29];

    // ---- workspace layout (total ~192.7 MB) ----
    char* ws = (char*)d_ws;
    float*          h       = (float*)ws;                           //  83,886,080 B
    float*          stats   = (float*)(ws + 83886080);              //   2,621,440 B
    unsigned short* y       = (unsigned short*)(ws + 86507520);     //  41,943,040 B (NTOK x 128 bf16)
    unsigned short* scratch = (unsigned short*)(ws + 128450560);    //  62,914,560 B (CHTOK x 384 bf16)
    unsigned short* wqT     = (unsigned short*)(ws + 191365120);    //     294,912 B
    unsigned short* outT    = (unsigned short*)(ws + 191660032);    //      98,304 B
    unsigned short* ff1T    = (unsigned short*)(ws + 191758336);    //     393,216 B
    unsigned short* ff2T    = (unsigned short*)(ws + 192151552);    //     393,216 B
    float*          partials= (float*)(ws + 192544768);             //     163,840 B
    float*          scal    = (float*)(ws + 192708608);             //         256 B

    pack_w_k<<<2304, 256, 0, stream>>>(qt_w, kt_w, qs_w, ks_w, v_w, out_w, ff_w1, ff_w2,
                                       wqT, outT, ff1T, ff2T);
    embed_k<<<81920, 256, 0, stream>>>(x, embed_w, embed_b, pos, h);

    // stats for mln1 of layer 0 (only standalone stats pass)
    mln_stats_k<<<40960, 256, 0, stream>>>(h, n1_pre_g, n1_pre_b, stats, partials);
    reduce_eps_k<<<1, 1024, 0, stream>>>(partials, 40960, scal);

    for (int i = 0; i < NLAY; ++i) {
        for (int c = 0; c < 2; ++c) {
            size_t off = (size_t)c * CHTOK;
            qkv_k<<<640, 256, 0, stream>>>(
                h + off*128, stats + off*4, scal,
                n1_pre_g + i*128, n1_pre_b + i*128, n1_g + i*128, n1_b + i*128,
                wqT + (size_t)i*49152, scratch);
            attn_k<<<2048, 256, 0, stream>>>(scratch, y + off*128, w_sigma + i);
            outproj_k<<<640, 256, 0, stream>>>(
                y + off*128, outT + (size_t)i*16384, out_b + i*128,
                h + off*128, n2_pre_g + i*128, n2_pre_b + i*128,
                stats + off*4, partials + c*640);
        }
        reduce_eps_k<<<1, 1024, 0, stream>>>(partials, 1280, scal);
        const float* npg = (i < NLAY-1) ? (n1_pre_g + (i+1)*128) : fn_pre_g;
        const float* npb = (i < NLAY-1) ? (n1_pre_b + (i+1)*128) : fn_pre_b;
        ffn_k<<<1280, 256, 0, stream>>>(
            h, stats, scal,
            n2_pre_g + i*128, n2_pre_b + i*128, n2_g + i*128, n2_b + i*128,
            ff1T + (size_t)i*65536, ff_b1 + i*512,
            ff2T + (size_t)i*65536, ff_b2 + i*128, h,
            npg, npb, stats, partials);
        reduce_eps_k<<<1, 1024, 0, stream>>>(partials, 1280, scal);
    }

    // ---- final mln apply + head ----
    mln_apply_k<<<20480, 256, 0, stream>>>(h, stats, scal, fn_pre_g, fn_pre_b, fn_g, fn_b, y);
    head_k<<<4096, 128, 0, stream>>>(y, traj_w, traj_b, (float*)d_out);
}